// Round 1
// baseline (1101.678 us; speedup 1.0000x reference)
//
#include <hip/hip_runtime.h>

#define B_   4
#define L_   8192
#define D_   2048
#define H_   32
#define WIN_ 1024
#define U_   512      // tokens per (window, parity) slice
#define PAD_ 68       // 64 + 4 pad: rows shift banks by 4 -> near-floor b128 patterns
#define QSC  0.125f   // 1/sqrt(64)^2... score scale folded into Q

// cross-lane add via DPP on the VALU pipe (compiler-managed hazards)
template <int CTRL>
__device__ __forceinline__ float dpp_add(float v) {
    int s = __builtin_amdgcn_update_dpp(0, __builtin_bit_cast(int, v), CTRL, 0xf, 0xf, true);
    return v + __builtin_bit_cast(float, s);
}
// sum over an aligned 8-lane group: xor1, xor2, then half-mirror acts as xor4
// once quads are uniform. 3 stages (vs 4 for the old 16-lane groups).
__device__ __forceinline__ float red8(float v) {
    v = dpp_add<0xB1>(v);    // quad_perm [1,0,3,2]  (xor 1)
    v = dpp_add<0x4E>(v);    // quad_perm [2,3,0,1]  (xor 2)
    v = dpp_add<0x141>(v);   // row_half_mirror      (xor 4 after uniformity)
    return v;
}

// 8-dim dot as two independent fma chains (ILP) + combine
__device__ __forceinline__ float dot8(const float4& a0, const float4& a1,
                                      const float4& b0, const float4& b1) {
    float s = a0.x * b0.x, t = a0.y * b0.y;
    s = fmaf(a0.z, b0.z, s); t = fmaf(a0.w, b0.w, t);
    s = fmaf(a1.x, b1.x, s); t = fmaf(a1.y, b1.y, t);
    s = fmaf(a1.z, b1.z, s); t = fmaf(a1.w, b1.w, t);
    return s + t;
}

__device__ __forceinline__ void fma4(float4& a, float s, const float4& b) {
    a.x = fmaf(s, b.x, a.x); a.y = fmaf(s, b.y, a.y);
    a.z = fmaf(s, b.z, a.z); a.w = fmaf(s, b.w, a.w);
}

__device__ __forceinline__ float4 mul4(const float4& a, float s) {
    return make_float4(a.x * s, a.y * s, a.z * s, a.w * s);
}

// K1: one block per (b, win, parity, head). 1024 threads = 128 pair-slots x
// 8 lanes (8 head-dims each); 2 in-block iterations cover all 256 query pairs
// against ONE LDS staging of the 512-row parity slice. 8 dims/lane halves the
// cross-lane reduce work per useful FMA vs the old 4-dim layout (3 DPP stages
// amortized over 16 FMAs instead of 4 stages over 8), which is where the VALU
// time was going (VALUBusy 76%, MfmaUtil 0). The (u, u+16) pair still shares
// its rate-3/4/5 key-row reads, keeping LDS traffic at the b128 floor.
__global__ __launch_bounds__(1024)
void ddattn_k1(const float* __restrict__ x, float* __restrict__ out,
               float* __restrict__ den) {
    const int bid = blockIdx.x;
    const int h   = bid & 31;
    const int p   = (bid >> 5) & 1;
    const int win = (bid >> 6) & 7;
    const int b   = bid >> 9;

    __shared__ float Xs[U_ * PAD_];
    const int t0 = win * WIN_;
    const float* xb = x + ((size_t)b * L_ + (size_t)(t0 + p)) * D_ + h * 64;

    for (int idx = threadIdx.x; idx < U_ * 16; idx += 1024) {
        const int row = idx >> 4, c = idx & 15;
        *(float4*)(&Xs[row * PAD_ + c * 4]) =
            *(const float4*)(xb + (size_t)row * (2 * D_) + c * 4);
    }
    __syncthreads();

    const int lane8 = threadIdx.x & 7;   // 8-dim slice within the head
    const int slot  = threadIdx.x >> 3;  // pair slot 0..127
    const int off   = lane8 * 8;         // dword offset of my dims (16B aligned)

#pragma unroll 1
    for (int qq = 0; qq < 2; qq++) {
        const int P  = qq * 128 + slot;                  // pair index 0..255
        const int u0 = (P & 15) | ((P >> 4) << 5);       // bit4 = 0
        const int u1 = u0 + 16;                          // bit4 = 1

        const float4 Qu00 = *(const float4*)(&Xs[u0 * PAD_ + off]);
        const float4 Qu01 = *(const float4*)(&Xs[u0 * PAD_ + off + 4]);
        const float4 Qu10 = *(const float4*)(&Xs[u1 * PAD_ + off]);
        const float4 Qu11 = *(const float4*)(&Xs[u1 * PAD_ + off + 4]);

        // scores use Q pre-scaled by 1/8 -> saves a mul per (q,k)
        const float4 Qs00 = mul4(Qu00, QSC), Qs01 = mul4(Qu01, QSC);
        const float4 Qs10 = mul4(Qu10, QSC), Qs11 = mul4(Qu11, QSC);

        // rate 0: probs == 1 -> out += x ; den = exp(|x|^2 / 8)
        float4 acc00 = Qu00, acc01 = Qu01, acc10 = Qu10, acc11 = Qu11;
        float den0 = __expf(red8(dot8(Qs00, Qs01, Qu00, Qu01)));
        float den1 = __expf(red8(dot8(Qs10, Qs11, Qu10, Qu11)));

        // rates 1,2: pair members have different groups -> per query
        auto rate_single = [&](const float4& qa, const float4& qb, int u,
                               float4& A0, float4& A1, float& dn, int i) {
            const int step = 1 << (i - 1), cnt = 1 << i;
            const int ub = ((u >> (2 * i - 1)) << (2 * i - 1)) | (u & (step - 1));
            const float* ptr = &Xs[ub * PAD_ + off];
            float4 E0 = make_float4(0, 0, 0, 0), E1 = make_float4(0, 0, 0, 0);
            float Dr = 0.f;
            for (int k = 0; k < cnt; k++) {
                const float4 R0 = *(const float4*)(ptr);
                const float4 R1 = *(const float4*)(ptr + 4);
                ptr += step * PAD_;
                const float e = __expf(red8(dot8(qa, qb, R0, R1)));
                Dr += e;
                fma4(E0, e, R0); fma4(E1, e, R1);
            }
            dn += Dr;
            const float inv = 1.0f / Dr;
            fma4(A0, inv, E0); fma4(A1, inv, E1);
        };
        rate_single(Qs00, Qs01, u0, acc00, acc01, den0, 1);
        rate_single(Qs00, Qs01, u0, acc00, acc01, den0, 2);
        rate_single(Qs10, Qs11, u1, acc10, acc11, den1, 1);
        rate_single(Qs10, Qs11, u1, acc10, acc11, den1, 2);

        // rates 3,4,5: the pair shares the group -> each key row read once,
        // feeds both queries' dot+accumulate (two independent VALU chains)
#pragma unroll
        for (int i = 3; i <= 5; i++) {
            const int step = 1 << (i - 1), cnt = 1 << i;
            const int ub = ((u0 >> (2 * i - 1)) << (2 * i - 1)) | (u0 & (step - 1));
            const float* ptr = &Xs[ub * PAD_ + off];
            float4 E00 = make_float4(0, 0, 0, 0), E01 = E00, E10 = E00, E11 = E00;
            float D0 = 0.f, D1 = 0.f;
#pragma unroll 4
            for (int k = 0; k < cnt; k++) {
                const float4 R0 = *(const float4*)(ptr);
                const float4 R1 = *(const float4*)(ptr + 4);
                ptr += step * PAD_;
                const float e0 = __expf(red8(dot8(Qs00, Qs01, R0, R1)));
                const float e1 = __expf(red8(dot8(Qs10, Qs11, R0, R1)));
                D0 += e0; D1 += e1;
                fma4(E00, e0, R0); fma4(E01, e0, R1);
                fma4(E10, e1, R0); fma4(E11, e1, R1);
            }
            den0 += D0; den1 += D1;
            const float i0 = 1.0f / D0, i1 = 1.0f / D1;
            fma4(acc00, i0, E00); fma4(acc01, i0, E01);
            fma4(acc10, i1, E10); fma4(acc11, i1, E11);
        }

        // write back (8 lanes x 32B contiguous per token -> coalesced 256B)
        const int tA = t0 + 2 * u0 + p;
        float* opA = out + ((size_t)b * L_ + tA) * D_ + h * 64 + off;
        *(float4*)opA = acc00; *(float4*)(opA + 4) = acc01;
        if (lane8 == 0) den[((size_t)b * L_ + tA) * H_ + h] = den0;

        const int tB = t0 + 2 * u1 + p;
        float* opB = out + ((size_t)b * L_ + tB) * D_ + h * 64 + off;
        *(float4*)opB = acc10; *(float4*)(opB + 4) = acc11;
        if (lane8 == 0) den[((size_t)b * L_ + tB) * H_ + h] = den1;
    }
}

// K2: per token, w = softmax over heads of den; scale the 2048-wide row.
// Rewritten: 16 tokens per 1024-thread block (2048 blocks instead of 16384
// two-token blocks -- the old version ran ~3.7x over its BW roofline).
// Weights computed once into LDS, then an 8-deep unrolled float4 RMW stream.
__global__ __launch_bounds__(1024)
void ddattn_k2(float* __restrict__ out, const float* __restrict__ den) {
    const int tid = threadIdx.x;
    const size_t t0 = (size_t)blockIdx.x * 16;   // 16 tokens per block
    __shared__ float sden[16][32];
    __shared__ float sw[16][32];
    if (tid < 512)
        (&sden[0][0])[tid] = den[t0 * H_ + tid];
    __syncthreads();
    if (tid < 512) {
        const int tt = tid >> 5, hh = tid & 31;
        float mx = -3.4e38f;
#pragma unroll
        for (int k = 0; k < H_; k++) mx = fmaxf(mx, sden[tt][k]);
        float s = 0.f;
#pragma unroll
        for (int k = 0; k < H_; k++) s += __expf(sden[tt][k] - mx);
        sw[tt][hh] = __expf(sden[tt][hh] - mx) / s;
    }
    __syncthreads();

    float4* o4 = (float4*)(out + t0 * D_);
#pragma unroll
    for (int c = 0; c < 8; c++) {
        const int idx = tid + 1024 * c;          // 8192 float4 = 16 tokens
        const float w = sw[idx >> 9][(idx >> 4) & 31];
        float4 vv = o4[idx];
        vv.x *= w; vv.y *= w; vv.z *= w; vv.w *= w;
        o4[idx] = vv;
    }
}

extern "C" void kernel_launch(void* const* d_in, const int* in_sizes, int n_in,
                              void* d_out, int out_size, void* d_ws, size_t ws_size,
                              hipStream_t stream) {
    const float* x = (const float*)d_in[0];
    float* out = (float*)d_out;
    float* den = (float*)d_ws;  // B*L*H fp32 = 4 MB scratch

    ddattn_k1<<<dim3(B_ * (L_ / WIN_) * 2 * H_), dim3(1024), 0, stream>>>(x, out, den);
    ddattn_k2<<<dim3(B_ * L_ / 16), dim3(1024), 0, stream>>>(out, den);
}

// Round 3
// 784.650 us; speedup vs baseline: 1.4040x; 1.4040x over previous
//
#include <hip/hip_runtime.h>

#define B_   4
#define L_   8192
#define D_   2048
#define H_   32
#define WIN_ 1024
#define U_   512      // tokens per (window, parity) slice
#define PAD_ 68       // 64 + 4 pad: row->bank shift of 4 keeps b128 reads near floor
#define QSC  0.125f   // score scale folded into Q

// cross-lane add via DPP on the VALU pipe
template <int CTRL>
__device__ __forceinline__ float dpp_add(float v) {
    int s = __builtin_amdgcn_update_dpp(0, __builtin_bit_cast(int, v), CTRL, 0xf, 0xf, true);
    return v + __builtin_bit_cast(float, s);
}
// sum over an aligned 8-lane group: xor1, xor2, then row_half_mirror (which
// mirrors WITHIN each 8-lane half: 0..3 <-> 4..7 at quad-uniform level).
// Verified on HW in the previous rounds (passed with this reduce).
__device__ __forceinline__ float red8(float v) {
    v = dpp_add<0xB1>(v);    // quad_perm [1,0,3,2]  (xor 1)
    v = dpp_add<0x4E>(v);    // quad_perm [2,3,0,1]  (xor 2)
    v = dpp_add<0x141>(v);   // row_half_mirror      (xor 4 after quad uniformity)
    return v;
}

// 8-dim dot as two independent fma chains (ILP) + combine
__device__ __forceinline__ float dot8(const float4& a0, const float4& a1,
                                      const float4& b0, const float4& b1) {
    float s = a0.x * b0.x, t = a0.y * b0.y;
    s = fmaf(a0.z, b0.z, s); t = fmaf(a0.w, b0.w, t);
    s = fmaf(a1.x, b1.x, s); t = fmaf(a1.y, b1.y, t);
    s = fmaf(a1.z, b1.z, s); t = fmaf(a1.w, b1.w, t);
    return s + t;
}

__device__ __forceinline__ void fma4(float4& a, float s, const float4& b) {
    a.x = fmaf(s, b.x, a.x); a.y = fmaf(s, b.y, a.y);
    a.z = fmaf(s, b.z, a.z); a.w = fmaf(s, b.w, a.w);
}

__device__ __forceinline__ float4 mul4(const float4& a, float s) {
    return make_float4(a.x * s, a.y * s, a.z * s, a.w * s);
}

// K1: one block per (b, win, parity, head). 1024 threads = 128 query-slots x
// 8 lanes (8 head-dims each); 4 in-block iterations cover the 512 queries
// against ONE LDS staging of the parity slice.
//
// vs round-0 (16 lanes/query, pair-shared): 8 dims/lane amortizes a 3-stage
// DPP reduce over 16 FMAs instead of 4 stages over 8 -> ~0.6x wave-instr per
// (q,k). vs round-1 (pair-shared at 8 dims): pair-sharing needed ~76 live
// floats and spilled 2.8 GB to scratch under the RA's 64-VGPR budget; this
// no-pair layout needs ~42 live floats -> zero spills. LDS traffic doubles
// for rates 3-5 (16.9 GB total) but stays at/below the VALU pipe cost.
__global__ __launch_bounds__(1024)
void ddattn_k1(const float* __restrict__ x, float* __restrict__ out,
               float* __restrict__ den) {
    const int bid = blockIdx.x;
    const int h   = bid & 31;
    const int p   = (bid >> 5) & 1;
    const int win = (bid >> 6) & 7;
    const int b   = bid >> 9;

    __shared__ float Xs[U_ * PAD_];
    const int t0 = win * WIN_;
    const float* xb = x + ((size_t)b * L_ + (size_t)(t0 + p)) * D_ + h * 64;

    for (int idx = threadIdx.x; idx < U_ * 16; idx += 1024) {
        const int row = idx >> 4, c = idx & 15;
        *(float4*)(&Xs[row * PAD_ + c * 4]) =
            *(const float4*)(xb + (size_t)row * (2 * D_) + c * 4);
    }
    __syncthreads();

    const int lane8 = threadIdx.x & 7;   // 8-dim slice within the head
    const int slot  = threadIdx.x >> 3;  // query slot 0..127
    const int off   = lane8 * 8;         // dword offset (16B aligned)

#pragma unroll 1
    for (int qq = 0; qq < 4; qq++) {
        const int u = qq * 128 + slot;

        // acc starts as the unscaled Qu (rate 0: probs==1 -> out += x);
        // Qs = Qu/8 folds the score scale; rate-0 den = exp(Qs . Qu).
        float4 acc0 = *(const float4*)(&Xs[u * PAD_ + off]);
        float4 acc1 = *(const float4*)(&Xs[u * PAD_ + off + 4]);
        const float4 Qs0 = mul4(acc0, QSC), Qs1 = mul4(acc1, QSC);
        float dn = __expf(red8(dot8(Qs0, Qs1, acc0, acc1)));

        // rates 1..5: group base ub, stride step, cnt keys
#pragma unroll
        for (int i = 1; i <= 5; i++) {
            const int step = 1 << (i - 1), cnt = 1 << i;
            const int ub = ((u >> (2 * i - 1)) << (2 * i - 1)) | (u & (step - 1));
            const float* ptr = &Xs[ub * PAD_ + off];
            float4 E0 = make_float4(0, 0, 0, 0), E1 = E0;
            float D = 0.f;
#pragma unroll 4
            for (int k = 0; k < cnt; k++) {
                const float4 R0 = *(const float4*)(ptr);
                const float4 R1 = *(const float4*)(ptr + 4);
                ptr += step * PAD_;
                const float e = __expf(red8(dot8(Qs0, Qs1, R0, R1)));
                D += e;
                fma4(E0, e, R0); fma4(E1, e, R1);
            }
            dn += D;
            const float inv = 1.0f / D;
            fma4(acc0, inv, E0); fma4(acc1, inv, E1);
        }

        // write back (8 lanes x 32B contiguous per token -> coalesced 256B)
        const int t = t0 + 2 * u + p;
        float* op = out + ((size_t)b * L_ + t) * D_ + h * 64 + off;
        *(float4*)op = acc0; *(float4*)(op + 4) = acc1;
        if (lane8 == 0) den[((size_t)b * L_ + t) * H_ + h] = dn;
    }
}

// K2: per token, w = softmax over heads of den; scale the 2048-wide row.
// Round-0 exact version (measured share ~322 us; the round-1 rewrite was no
// better). 2 tokens per 256-thread block; weights once into LDS, then a pure
// streaming RMW.
__global__ __launch_bounds__(256)
void ddattn_k2(float* __restrict__ out, const float* __restrict__ den) {
    const int tok0 = blockIdx.x * 2;
    __shared__ float sden[2][H_];
    __shared__ float w2[2][H_];
    if (threadIdx.x < 64)
        sden[threadIdx.x >> 5][threadIdx.x & 31] = den[(size_t)tok0 * H_ + threadIdx.x];
    __syncthreads();
    if (threadIdx.x < 64) {
        const int tt = threadIdx.x >> 5, hh = threadIdx.x & 31;
        float mx = -3.4e38f;
#pragma unroll
        for (int k = 0; k < H_; k++) mx = fmaxf(mx, sden[tt][k]);
        float s = 0.f;
#pragma unroll
        for (int k = 0; k < H_; k++) s += __expf(sden[tt][k] - mx);
        w2[tt][hh] = __expf(sden[tt][hh] - mx) / s;
    }
    __syncthreads();

    float4* o4 = (float4*)(out + (size_t)tok0 * D_);
#pragma unroll
    for (int c = 0; c < 4; c++) {
        const int idx = threadIdx.x + 256 * c;        // 1024 float4 = 2 tokens
        const float w = w2[idx >> 9][(idx >> 4) & 31];
        float4 vv = o4[idx];
        vv.x *= w; vv.y *= w; vv.z *= w; vv.w *= w;
        o4[idx] = vv;
    }
}

extern "C" void kernel_launch(void* const* d_in, const int* in_sizes, int n_in,
                              void* d_out, int out_size, void* d_ws, size_t ws_size,
                              hipStream_t stream) {
    const float* x = (const float*)d_in[0];
    float* out = (float*)d_out;
    float* den = (float*)d_ws;  // B*L*H fp32 = 4 MB scratch

    ddattn_k1<<<dim3(B_ * (L_ / WIN_) * 2 * H_), dim3(1024), 0, stream>>>(x, out, den);
    ddattn_k2<<<dim3(B_ * L_ / 2), dim3(256), 0, stream>>>(out, den);
}